// Round 1
// baseline (395.232 us; speedup 1.0000x reference)
//
#include <hip/hip_runtime.h>
#include <stdint.h>

typedef unsigned long long u64;
typedef unsigned int u32;

constexpr int kC  = 256;
constexpr int kHW = 3136;           // 56*56
constexpr int kN  = 32;
constexpr int kP  = kN * kHW;       // 100352 spatial positions
constexpr int kPB = 256;            // positions per block
constexpr int kBlocks = kP / kPB;   // 392

// d_ws layout (bytes):
constexpr size_t OFF_T     = 0;      // u64 [4][256]  packed w-sign planes
constexpr size_t OFF_SCALE = 8192;   // f32 [256]
constexpr size_t OFF_SUMD  = 9216;   // i64 [256]  sum of dot
constexpr size_t OFF_SUMD2 = 11264;  // i64 [256]  sum of dot^2
constexpr size_t OFF_S     = 13312;  // u64 [4][kP] packed x-sign planes (SoA)

// ---------------------------------------------------------------------------
// Kernel 0: pack w signs, compute per-out-channel scale, zero stat sums.
// ---------------------------------------------------------------------------
__global__ __launch_bounds__(256) void prep_kernel(
    const float* __restrict__ w, char* __restrict__ ws) {
  u64*   T     = (u64*)(ws + OFF_T);
  float* scale = (float*)(ws + OFF_SCALE);
  u64*   sumd  = (u64*)(ws + OFF_SUMD);
  u64*   sumd2 = (u64*)(ws + OFF_SUMD2);

  int o = threadIdx.x;
  const float* wr = w + o * kC;
  float acc = 0.0f;
  u64 bits[4] = {0, 0, 0, 0};
#pragma unroll 8
  for (int c = 0; c < kC; ++c) {
    float v = wr[c];
    acc += fabsf(v);
    if (v >= 0.0f) bits[c >> 6] |= (1ull << (c & 63));
  }
  scale[o] = acc * (1.0f / 256.0f);
#pragma unroll
  for (int k = 0; k < 4; ++k) T[k * 256 + o] = bits[k];
  sumd[o]  = 0ull;
  sumd2[o] = 0ull;
}

// ---------------------------------------------------------------------------
// Kernel 1: pack sign(x + bias0) into S, and accumulate exact integer
// per-channel sum(dot) and sum(dot^2) via xor+popc (dot = 2*(128 - popc)).
// ---------------------------------------------------------------------------
__global__ __launch_bounds__(256) void pack_stats_kernel(
    const float* __restrict__ x, const float* __restrict__ bias0,
    char* __restrict__ ws) {
  __shared__ u64   ldsS[256][4];
  __shared__ float ldsB[256];

  int t = threadIdx.x;
  ldsB[t] = bias0[t];
  __syncthreads();

  u32 p  = blockIdx.x * 256u + (u32)t;
  u32 n  = p / kHW;
  u32 hw = p - n * kHW;
  const float* xp = x + (size_t)n * kC * kHW + hw;

  u32 b[8] = {0, 0, 0, 0, 0, 0, 0, 0};
#pragma unroll 16
  for (int c = 0; c < kC; ++c) {
    float v = xp[(size_t)c * kHW] + ldsB[c];
    if (v >= 0.0f) b[c >> 5] |= (1u << (c & 31));
  }

  u64 bits[4];
#pragma unroll
  for (int k = 0; k < 4; ++k)
    bits[k] = (u64)b[2 * k] | ((u64)b[2 * k + 1] << 32);

  u64* S = (u64*)(ws + OFF_S);
#pragma unroll
  for (int k = 0; k < 4; ++k) {
    S[(size_t)k * kP + p] = bits[k];   // SoA planes: coalesced 8B/lane
    ldsS[t][k] = bits[k];
  }
  __syncthreads();

  // Stats phase: thread t == output channel o over this block's 256 positions.
  const u64* T = (const u64*)(ws + OFF_T);
  u64 t0 = T[t], t1 = T[256 + t], t2 = T[512 + t], t3 = T[768 + t];
  int summ = 0, summ2 = 0;
#pragma unroll 4
  for (int pp = 0; pp < 256; ++pp) {
    int k = __popcll(ldsS[pp][0] ^ t0) + __popcll(ldsS[pp][1] ^ t1) +
            __popcll(ldsS[pp][2] ^ t2) + __popcll(ldsS[pp][3] ^ t3);
    int m = 128 - k;    // dot = 2*m, exact integer
    summ  += m;
    summ2 += m * m;
  }
  u64* sumd  = (u64*)(ws + OFF_SUMD);
  u64* sumd2 = (u64*)(ws + OFF_SUMD2);
  atomicAdd(&sumd[t],  (u64)(long long)(2 * summ));
  atomicAdd(&sumd2[t], (u64)(long long)(4 * summ2));
}

// ---------------------------------------------------------------------------
// Kernel 2: BN coefs from exact sums, recompute dots from S, fuse
// residual + bias1 + PReLU + bias2, write out.
//   u   = gamma*rs*scale*dot + (beta - gamma*rs*mu + bias1) + x
//   out = (u>0 ? u : alpha*u) + bias2
// ---------------------------------------------------------------------------
__global__ __launch_bounds__(256) void finalize_kernel(
    const float* __restrict__ x, const float* __restrict__ gamma,
    const float* __restrict__ beta, const float* __restrict__ bias1,
    const float* __restrict__ alpha, const float* __restrict__ bias2,
    const char* __restrict__ ws, float* __restrict__ out) {
  __shared__ u64    ldsT[4][256];
  __shared__ float4 ldsC[256];  // {2*cA, cB, alpha, bias2}

  int t = threadIdx.x;
  {
    const u64* T = (const u64*)(ws + OFF_T);
#pragma unroll
    for (int k = 0; k < 4; ++k) ldsT[k][t] = T[k * 256 + t];

    const float*     scale = (const float*)(ws + OFF_SCALE);
    const long long* sumd  = (const long long*)(ws + OFF_SUMD);
    const long long* sumd2 = (const long long*)(ws + OFF_SUMD2);
    double inv  = 1.0 / (double)kP;
    double md   = (double)sumd[t] * inv;    // E[dot]
    double e2   = (double)sumd2[t] * inv;   // E[dot^2]
    double vard = e2 - md * md;             // Var[dot]
    float sc  = scale[t];
    float mu  = sc * (float)md;
    float var = sc * sc * (float)vard;
    float rs  = rsqrtf(var + 1e-5f);
    float g   = gamma[t];
    float cA  = g * rs * sc;
    float cB  = beta[t] - g * rs * mu + bias1[t];
    ldsC[t] = make_float4(2.0f * cA, cB, alpha[t], bias2[t]);
  }
  __syncthreads();

  u32 p  = blockIdx.x * 256u + (u32)t;
  u32 n  = p / kHW;
  u32 hw = p - n * kHW;

  const u64* S = (const u64*)(ws + OFF_S);
  u64 s0 = S[p], s1 = S[kP + p], s2 = S[2 * kP + p], s3 = S[3 * kP + p];

  const float* xp = x   + (size_t)n * kC * kHW + hw;
  float*       op = out + (size_t)n * kC * kHW + hw;

#pragma unroll 4
  for (int o = 0; o < kC; ++o) {
    int k = __popcll(s0 ^ ldsT[0][o]) + __popcll(s1 ^ ldsT[1][o]) +
            __popcll(s2 ^ ldsT[2][o]) + __popcll(s3 ^ ldsT[3][o]);
    float m  = (float)(128 - k);           // dot = 2*m (2x folded into cc.x)
    float4 cc = ldsC[o];
    float xv = xp[(size_t)o * kHW];
    float u  = fmaf(cc.x, m, cc.y) + xv;
    float r  = u > 0.0f ? u : cc.z * u;
    op[(size_t)o * kHW] = r + cc.w;
  }
}

extern "C" void kernel_launch(void* const* d_in, const int* in_sizes, int n_in,
                              void* d_out, int out_size, void* d_ws, size_t ws_size,
                              hipStream_t stream) {
  const float* x     = (const float*)d_in[0];
  const float* bias0 = (const float*)d_in[1];
  const float* w     = (const float*)d_in[2];
  const float* gamma = (const float*)d_in[3];
  const float* beta  = (const float*)d_in[4];
  const float* bias1 = (const float*)d_in[5];
  const float* alpha = (const float*)d_in[6];
  const float* bias2 = (const float*)d_in[7];
  float* out = (float*)d_out;
  char*  ws  = (char*)d_ws;

  hipLaunchKernelGGL(prep_kernel, dim3(1), dim3(256), 0, stream, w, ws);
  hipLaunchKernelGGL(pack_stats_kernel, dim3(kBlocks), dim3(256), 0, stream,
                     x, bias0, ws);
  hipLaunchKernelGGL(finalize_kernel, dim3(kBlocks), dim3(256), 0, stream,
                     x, gamma, beta, bias1, alpha, bias2, ws, out);
}

// Round 2
// 278.117 us; speedup vs baseline: 1.4211x; 1.4211x over previous
//
#include <hip/hip_runtime.h>
#include <stdint.h>

typedef unsigned long long u64;
typedef unsigned int u32;

constexpr int kC  = 256;
constexpr int kHW = 3136;           // 56*56
constexpr int kN  = 32;
constexpr int kP  = kN * kHW;       // 100352 spatial positions
constexpr int kPB = 64;             // positions per block (64 | 3136)
constexpr int kBlocks = kP / kPB;   // 1568

// d_ws layout (bytes):
constexpr size_t OFF_T     = 0;      // u64 [4][256]  packed w-sign planes
constexpr size_t OFF_SCALE = 8192;   // f32 [256]
constexpr size_t OFF_SUMD  = 9216;   // i64 [256]  sum of dot
constexpr size_t OFF_SUMD2 = 11264;  // i64 [256]  sum of dot^2
constexpr size_t OFF_S     = 13312;  // u64 [4][kP] packed x-sign planes (SoA)

// ---------------------------------------------------------------------------
// Kernel 0: pack w signs, compute per-out-channel scale, zero stat sums.
// ---------------------------------------------------------------------------
__global__ __launch_bounds__(256) void prep_kernel(
    const float* __restrict__ w, char* __restrict__ ws) {
  u64*   T     = (u64*)(ws + OFF_T);
  float* scale = (float*)(ws + OFF_SCALE);
  u64*   sumd  = (u64*)(ws + OFF_SUMD);
  u64*   sumd2 = (u64*)(ws + OFF_SUMD2);

  int o = threadIdx.x;
  const float* wr = w + o * kC;
  float acc = 0.0f;
  u64 bits[4] = {0, 0, 0, 0};
#pragma unroll 8
  for (int c = 0; c < kC; ++c) {
    float v = wr[c];
    acc += fabsf(v);
    if (v >= 0.0f) bits[c >> 6] |= (1ull << (c & 63));
  }
  scale[o] = acc * (1.0f / 256.0f);
#pragma unroll
  for (int k = 0; k < 4; ++k) T[k * 256 + o] = bits[k];
  sumd[o]  = 0ull;
  sumd2[o] = 0ull;
}

// ---------------------------------------------------------------------------
// Kernel 1: block = 64 positions x 4 channel-chunks (chunk is wave-uniform).
// Pack sign(x + bias0) into S plane `chunk`; then per-channel exact integer
// stats over the block's 64 positions via xor+popc (dot = 2*(128 - popc)).
// ---------------------------------------------------------------------------
__global__ __launch_bounds__(256) void pack_stats_kernel(
    const float* __restrict__ x, const float* __restrict__ bias0,
    char* __restrict__ ws) {
  __shared__ u64 ldsS[4][kPB];   // plane-major: 8B lane stride, conflict-free

  int t     = threadIdx.x;
  int pos   = t & 63;            // lane -> position (coalesced x)
  int chunk = t >> 6;            // wave-uniform channel chunk

  u32 p  = blockIdx.x * (u32)kPB + (u32)pos;
  u32 n  = p / kHW;
  u32 hw = p - n * kHW;
  const float* xp = x + (size_t)n * kC * kHW + (size_t)(chunk * 64) * kHW + hw;
  const float* bp = bias0 + chunk * 64;   // wave-uniform -> scalar loads

  u64 bits = 0;
#pragma unroll 16
  for (int i = 0; i < 64; ++i) {
    float v = xp[(size_t)i * kHW] + bp[i];
    if (v >= 0.0f) bits |= (1ull << i);
  }

  u64* S = (u64*)(ws + OFF_S);
  S[(size_t)chunk * kP + p] = bits;   // coalesced 8B/lane
  ldsS[chunk][pos] = bits;
  __syncthreads();

  // Stats phase: thread t == output channel o over this block's 64 positions.
  const u64* T = (const u64*)(ws + OFF_T);
  u64 t0 = T[t], t1 = T[256 + t], t2 = T[512 + t], t3 = T[768 + t];
  int summ = 0, summ2 = 0;
#pragma unroll 8
  for (int pp = 0; pp < kPB; ++pp) {
    int k = __popcll(ldsS[0][pp] ^ t0) + __popcll(ldsS[1][pp] ^ t1) +
            __popcll(ldsS[2][pp] ^ t2) + __popcll(ldsS[3][pp] ^ t3);
    int m = 128 - k;    // dot = 2*m, exact integer
    summ  += m;
    summ2 += m * m;
  }
  u64* sumd  = (u64*)(ws + OFF_SUMD);
  u64* sumd2 = (u64*)(ws + OFF_SUMD2);
  atomicAdd(&sumd[t],  (u64)(long long)(2 * summ));
  atomicAdd(&sumd2[t], (u64)(long long)(4 * summ2));
}

// ---------------------------------------------------------------------------
// Kernel 2: BN coefs from exact sums, recompute dots from S, fuse
// residual + bias1 + PReLU + bias2, write out. Same 64-pos x 4-chunk map.
//   u   = gamma*rs*scale*dot + (beta - gamma*rs*mu + bias1) + x
//   out = (u>0 ? u : alpha*u) + bias2
// ---------------------------------------------------------------------------
__global__ __launch_bounds__(256) void finalize_kernel(
    const float* __restrict__ x, const float* __restrict__ gamma,
    const float* __restrict__ beta, const float* __restrict__ bias1,
    const float* __restrict__ alpha, const float* __restrict__ bias2,
    const char* __restrict__ ws, float* __restrict__ out) {
  __shared__ u64    ldsT[4][256];
  __shared__ float4 ldsC[256];  // {2*cA, cB, alpha, bias2}

  int t = threadIdx.x;
  {
    const u64* T = (const u64*)(ws + OFF_T);
#pragma unroll
    for (int k = 0; k < 4; ++k) ldsT[k][t] = T[k * 256 + t];

    const float*     scale = (const float*)(ws + OFF_SCALE);
    const long long* sumd  = (const long long*)(ws + OFF_SUMD);
    const long long* sumd2 = (const long long*)(ws + OFF_SUMD2);
    double inv  = 1.0 / (double)kP;
    double md   = (double)sumd[t] * inv;    // E[dot]
    double e2   = (double)sumd2[t] * inv;   // E[dot^2]
    double vard = e2 - md * md;             // Var[dot]
    float sc  = scale[t];
    float mu  = sc * (float)md;
    float var = sc * sc * (float)vard;
    float rs  = rsqrtf(var + 1e-5f);
    float g   = gamma[t];
    float cA  = g * rs * sc;
    float cB  = beta[t] - g * rs * mu + bias1[t];
    ldsC[t] = make_float4(2.0f * cA, cB, alpha[t], bias2[t]);
  }
  __syncthreads();

  int pos   = t & 63;
  int chunk = t >> 6;
  u32 p  = blockIdx.x * (u32)kPB + (u32)pos;
  u32 n  = p / kHW;
  u32 hw = p - n * kHW;

  const u64* S = (const u64*)(ws + OFF_S);
  u64 s0 = S[p], s1 = S[kP + p], s2 = S[2 * kP + p], s3 = S[3 * kP + p];

  const float* xp = x   + (size_t)n * kC * kHW + (size_t)(chunk * 64) * kHW + hw;
  float*       op = out + (size_t)n * kC * kHW + (size_t)(chunk * 64) * kHW + hw;

#pragma unroll 8
  for (int i = 0; i < 64; ++i) {
    int o = chunk * 64 + i;     // wave-uniform -> LDS broadcast reads
    int k = __popcll(s0 ^ ldsT[0][o]) + __popcll(s1 ^ ldsT[1][o]) +
            __popcll(s2 ^ ldsT[2][o]) + __popcll(s3 ^ ldsT[3][o]);
    float m  = (float)(128 - k);           // dot = 2*m (2x folded into cc.x)
    float4 cc = ldsC[o];
    float xv = xp[(size_t)i * kHW];
    float u  = fmaf(cc.x, m, cc.y) + xv;
    float r  = u > 0.0f ? u : cc.z * u;
    op[(size_t)i * kHW] = r + cc.w;
  }
}

extern "C" void kernel_launch(void* const* d_in, const int* in_sizes, int n_in,
                              void* d_out, int out_size, void* d_ws, size_t ws_size,
                              hipStream_t stream) {
  const float* x     = (const float*)d_in[0];
  const float* bias0 = (const float*)d_in[1];
  const float* w     = (const float*)d_in[2];
  const float* gamma = (const float*)d_in[3];
  const float* beta  = (const float*)d_in[4];
  const float* bias1 = (const float*)d_in[5];
  const float* alpha = (const float*)d_in[6];
  const float* bias2 = (const float*)d_in[7];
  float* out = (float*)d_out;
  char*  ws  = (char*)d_ws;

  hipLaunchKernelGGL(prep_kernel, dim3(1), dim3(256), 0, stream, w, ws);
  hipLaunchKernelGGL(pack_stats_kernel, dim3(kBlocks), dim3(256), 0, stream,
                     x, bias0, ws);
  hipLaunchKernelGGL(finalize_kernel, dim3(kBlocks), dim3(256), 0, stream,
                     x, gamma, beta, bias1, alpha, bias2, ws, out);
}

// Round 3
// 257.586 us; speedup vs baseline: 1.5344x; 1.0797x over previous
//
#include <hip/hip_runtime.h>
#include <stdint.h>

typedef unsigned long long u64;
typedef unsigned int u32;

constexpr int kC  = 256;
constexpr int kHW = 3136;           // 56*56
constexpr int kN  = 32;
constexpr int kP  = kN * kHW;       // 100352 spatial positions
constexpr int kPosB = 128;          // positions per block (pack/stats/finalize)
constexpr int kBlocksP = kP / kPosB; // 784

// d_ws layout (bytes):
constexpr size_t OFF_T     = 0;      // u64 [4][256]  packed w-sign planes (plane-major)
constexpr size_t OFF_SCALE = 8192;   // f32 [256]
constexpr size_t OFF_SUMD  = 9216;   // i64 [256]  sum of dot
constexpr size_t OFF_SUMD2 = 11264;  // i64 [256]  sum of dot^2
constexpr size_t OFF_S     = 13312;  // u64 [4][kP] packed x-sign planes (SoA), 16B-aligned

struct alignas(16) U64x2 { u64 x, y; };

// ---------------------------------------------------------------------------
// Kernel 0: pack w signs + per-row scale. 16 blocks x 256 thr.
// lane = column within 64-wide chunk -> coalesced loads; __ballot gives the
// packed T plane directly; scale via wave shuffle-reduce. Block 0 zeros sums.
// ---------------------------------------------------------------------------
__global__ __launch_bounds__(256) void prep_kernel(
    const float* __restrict__ w, char* __restrict__ ws) {
  u64*   T     = (u64*)(ws + OFF_T);
  float* scale = (float*)(ws + OFF_SCALE);
  u64*   sumd  = (u64*)(ws + OFF_SUMD);
  u64*   sumd2 = (u64*)(ws + OFF_SUMD2);

  int t = threadIdx.x;
  int k = t >> 6, lane = t & 63;
  int b = blockIdx.x;
  if (b == 0) { sumd[t] = 0ull; sumd2[t] = 0ull; }

  __shared__ float part[4][16];
#pragma unroll
  for (int i = 0; i < 16; ++i) {
    int o = b * 16 + i;
    float v = w[o * kC + k * 64 + lane];   // 256B/wave, coalesced
    u64 m = __ballot(v >= 0.0f);           // bit lane = sign -> T plane k
    float a = fabsf(v);
#pragma unroll
    for (int s = 32; s > 0; s >>= 1) a += __shfl_xor(a, s, 64);
    if (lane == 0) { T[k * 256 + o] = m; part[k][i] = a; }
  }
  __syncthreads();
  if (t < 16) {
    int o = b * 16 + t;
    scale[o] = (part[0][t] + part[1][t] + part[2][t] + part[3][t]) * (1.0f / 256.0f);
  }
}

// ---------------------------------------------------------------------------
// Kernel 1: pure sign-pack. block = 4 chunks x 64 lanes, 2 positions/lane
// via float2 (512B/wave loads). Grid 784 -> ~3 blocks/CU.
// ---------------------------------------------------------------------------
__global__ __launch_bounds__(256) void pack_kernel(
    const float* __restrict__ x, const float* __restrict__ bias0,
    char* __restrict__ ws) {
  int t = threadIdx.x;
  int k = __builtin_amdgcn_readfirstlane(t >> 6);  // wave-uniform chunk
  int lane = t & 63;

  u32 p  = blockIdx.x * (u32)kPosB + 2u * lane;    // handles p, p+1
  u32 n  = p / kHW;
  u32 hw = p - n * kHW;
  const float* xp = x + (size_t)n * kC * kHW + (size_t)(k * 64) * kHW + hw;
  const float* bp = bias0 + k * 64;                // uniform -> s_load

  u64 m0 = 0, m1 = 0;
#pragma unroll 16
  for (int i = 0; i < 64; ++i) {
    float2 v = *(const float2*)(xp + (size_t)i * kHW);
    float bb = bp[i];
    m0 |= (u64)(v.x + bb >= 0.0f) << i;
    m1 |= (u64)(v.y + bb >= 0.0f) << i;
  }
  u64* S = (u64*)(ws + OFF_S);
  U64x2 st; st.x = m0; st.y = m1;
  *(U64x2*)&S[(size_t)k * kP + p] = st;            // 16B/lane, coalesced
}

// ---------------------------------------------------------------------------
// Kernel 2: global stats. thread = output channel o; positions addressed
// uniformly (no threadIdx) -> scalar s_load broadcasts of S; pure VALU
// xor/popc. One atomic pair per (block, o).
// ---------------------------------------------------------------------------
__global__ __launch_bounds__(256) void stats_kernel(char* __restrict__ ws) {
  int o = threadIdx.x;
  const u64* T = (const u64*)(ws + OFF_T);
  u64 t0 = T[o], t1 = T[256 + o], t2 = T[512 + o], t3 = T[768 + o];
  const u64* S = (const u64*)(ws + OFF_S);
  u32 pb = blockIdx.x * (u32)kPosB;

  int summ = 0, summ2 = 0;
#pragma unroll 8
  for (int j = 0; j < kPosB; j += 2) {
    u32 p = pb + j;                                  // uniform -> s_load_dwordx4
    U64x2 a0 = *(const U64x2*)&S[p];
    U64x2 a1 = *(const U64x2*)&S[kP + p];
    U64x2 a2 = *(const U64x2*)&S[2 * kP + p];
    U64x2 a3 = *(const U64x2*)&S[3 * kP + p];
    int ka = __popcll(a0.x ^ t0) + __popcll(a1.x ^ t1) +
             __popcll(a2.x ^ t2) + __popcll(a3.x ^ t3);
    int kb = __popcll(a0.y ^ t0) + __popcll(a1.y ^ t1) +
             __popcll(a2.y ^ t2) + __popcll(a3.y ^ t3);
    int ma = 128 - ka, mb = 128 - kb;
    summ  += ma + mb;
    summ2 += ma * ma + mb * mb;
  }
  atomicAdd((u64*)(ws + OFF_SUMD) + o,  (u64)(long long)(2 * summ));
  atomicAdd((u64*)(ws + OFF_SUMD2) + o, (u64)(long long)(4 * summ2));
}

// ---------------------------------------------------------------------------
// Kernel 3: BN coefs + fused epilogue. Same float2 position mapping as pack;
// masks for both positions held in registers; T/coefs broadcast from LDS.
//   u   = 2*cA*m + cB + x ;  out = (u>0 ? u : alpha*u) + bias2
// ---------------------------------------------------------------------------
__global__ __launch_bounds__(256) void finalize_kernel(
    const float* __restrict__ x, const float* __restrict__ gamma,
    const float* __restrict__ beta, const float* __restrict__ bias1,
    const float* __restrict__ alpha, const float* __restrict__ bias2,
    const char* __restrict__ ws, float* __restrict__ out) {
  __shared__ u64    ldsT[256][4];   // [o][plane]: 32B/o -> 2x ds_read_b128
  __shared__ float4 ldsC[256];      // {2*cA, cB, alpha, bias2}

  int t = threadIdx.x;
  {
    const u64* T = (const u64*)(ws + OFF_T);
#pragma unroll
    for (int q = 0; q < 4; ++q) ldsT[t][q] = T[q * 256 + t];

    const float*     scale = (const float*)(ws + OFF_SCALE);
    const long long* sumd  = (const long long*)(ws + OFF_SUMD);
    const long long* sumd2 = (const long long*)(ws + OFF_SUMD2);
    double inv  = 1.0 / (double)kP;
    double md   = (double)sumd[t] * inv;
    double e2   = (double)sumd2[t] * inv;
    double vard = e2 - md * md;
    float sc  = scale[t];
    float mu  = sc * (float)md;
    float var = sc * sc * (float)vard;
    float rs  = rsqrtf(var + 1e-5f);
    float g   = gamma[t];
    float cA  = g * rs * sc;
    float cB  = beta[t] - g * rs * mu + bias1[t];
    ldsC[t] = make_float4(2.0f * cA, cB, alpha[t], bias2[t]);
  }
  __syncthreads();

  int k = __builtin_amdgcn_readfirstlane(t >> 6);
  int lane = t & 63;
  u32 p  = blockIdx.x * (u32)kPosB + 2u * lane;
  u32 n  = p / kHW;
  u32 hw = p - n * kHW;

  const u64* S = (const u64*)(ws + OFF_S);
  U64x2 s0 = *(const U64x2*)&S[p];          // 16B/lane vector loads
  U64x2 s1 = *(const U64x2*)&S[kP + p];
  U64x2 s2 = *(const U64x2*)&S[2 * kP + p];
  U64x2 s3 = *(const U64x2*)&S[3 * kP + p];

  const float* xp = x   + (size_t)n * kC * kHW + (size_t)(k * 64) * kHW + hw;
  float*       op = out + (size_t)n * kC * kHW + (size_t)(k * 64) * kHW + hw;

#pragma unroll 8
  for (int i = 0; i < 64; ++i) {
    int o = k * 64 + i;                      // wave-uniform -> LDS broadcast
    u64 w0 = ldsT[o][0], w1 = ldsT[o][1], w2 = ldsT[o][2], w3 = ldsT[o][3];
    int ka = __popcll(s0.x ^ w0) + __popcll(s1.x ^ w1) +
             __popcll(s2.x ^ w2) + __popcll(s3.x ^ w3);
    int kb = __popcll(s0.y ^ w0) + __popcll(s1.y ^ w1) +
             __popcll(s2.y ^ w2) + __popcll(s3.y ^ w3);
    float4 cc = ldsC[o];
    float2 xv = *(const float2*)(xp + (size_t)i * kHW);
    float u0 = fmaf(cc.x, (float)(128 - ka), cc.y) + xv.x;
    float u1 = fmaf(cc.x, (float)(128 - kb), cc.y) + xv.y;
    float r0 = u0 > 0.0f ? u0 : cc.z * u0;
    float r1 = u1 > 0.0f ? u1 : cc.z * u1;
    float2 ov; ov.x = r0 + cc.w; ov.y = r1 + cc.w;
    *(float2*)(op + (size_t)i * kHW) = ov;
  }
}

extern "C" void kernel_launch(void* const* d_in, const int* in_sizes, int n_in,
                              void* d_out, int out_size, void* d_ws, size_t ws_size,
                              hipStream_t stream) {
  const float* x     = (const float*)d_in[0];
  const float* bias0 = (const float*)d_in[1];
  const float* w     = (const float*)d_in[2];
  const float* gamma = (const float*)d_in[3];
  const float* beta  = (const float*)d_in[4];
  const float* bias1 = (const float*)d_in[5];
  const float* alpha = (const float*)d_in[6];
  const float* bias2 = (const float*)d_in[7];
  float* out = (float*)d_out;
  char*  ws  = (char*)d_ws;

  hipLaunchKernelGGL(prep_kernel, dim3(16), dim3(256), 0, stream, w, ws);
  hipLaunchKernelGGL(pack_kernel, dim3(kBlocksP), dim3(256), 0, stream,
                     x, bias0, ws);
  hipLaunchKernelGGL(stats_kernel, dim3(kBlocksP), dim3(256), 0, stream, ws);
  hipLaunchKernelGGL(finalize_kernel, dim3(kBlocksP), dim3(256), 0, stream,
                     x, gamma, beta, bias1, alpha, bias2, ws, out);
}

// Round 4
// 242.342 us; speedup vs baseline: 1.6309x; 1.0629x over previous
//
#include <hip/hip_runtime.h>
#include <stdint.h>

typedef unsigned long long u64;
typedef unsigned int u32;

constexpr int kC  = 256;
constexpr int kHW = 3136;             // 56*56
constexpr int kN  = 32;
constexpr int kP  = kN * kHW;         // 100352 spatial positions
constexpr int kPosPk = 64;            // positions per pack/finalize block
constexpr int kBlkPk = kP / kPosPk;   // 1568  (~24 waves/CU)
constexpr int kPosSt = 128;           // positions per stats block
constexpr int kBlkSt = kP / kPosSt;   // 784

// d_ws layout (bytes):
constexpr size_t OFF_T     = 0;      // u64 [4][256]  packed w-sign planes (plane-major)
constexpr size_t OFF_SCALE = 8192;   // f32 [256]
constexpr size_t OFF_SUMD  = 9216;   // i64 [256]  sum of dot
constexpr size_t OFF_SUMD2 = 11264;  // i64 [256]  sum of dot^2
constexpr size_t OFF_S     = 13312;  // u64 [4][kP] packed x-sign planes (SoA), 16B-aligned

struct alignas(16) U64x2 { u64 x, y; };

// ---------------------------------------------------------------------------
// Kernel 1: sign-pack x (+ folded-in w-prep on blocks 0..15).
// block = 4 chunks x 64 lanes, 1 position/lane. Grid 1568 -> ~24 waves/CU.
// x loads are non-temporal (pure stream, keep S resident in L2).
// ---------------------------------------------------------------------------
__global__ __launch_bounds__(256) void pack_kernel(
    const float* __restrict__ x, const float* __restrict__ bias0,
    const float* __restrict__ w, char* __restrict__ ws) {
  int t = threadIdx.x;
  int b = blockIdx.x;

  // ---- folded prep: blocks 0..15 build T + scale; block 0 zeros sums ----
  if (b < 16) {
    u64*   T     = (u64*)(ws + OFF_T);
    float* scale = (float*)(ws + OFF_SCALE);
    int kk = t >> 6, ln = t & 63;
    if (b == 0) {
      ((u64*)(ws + OFF_SUMD))[t]  = 0ull;
      ((u64*)(ws + OFF_SUMD2))[t] = 0ull;
    }
    __shared__ float part[4][16];
#pragma unroll
    for (int i = 0; i < 16; ++i) {
      int o = b * 16 + i;
      float v = w[o * kC + kk * 64 + ln];   // coalesced 256B/wave
      u64 m = __ballot(v >= 0.0f);
      float a = fabsf(v);
#pragma unroll
      for (int s = 32; s > 0; s >>= 1) a += __shfl_xor(a, s, 64);
      if (ln == 0) { T[kk * 256 + o] = m; part[kk][i] = a; }
    }
    __syncthreads();
    if (t < 16) {
      int o = b * 16 + t;
      scale[o] = (part[0][t] + part[1][t] + part[2][t] + part[3][t]) * (1.0f / 256.0f);
    }
  }

  // ---- pack ----
  int k    = __builtin_amdgcn_readfirstlane(t >> 6);  // wave-uniform chunk
  int lane = t & 63;
  u32 p  = (u32)b * (u32)kPosPk + (u32)lane;
  u32 n  = p / kHW;
  u32 hw = p - n * kHW;
  const float* xp = x + (size_t)n * kC * kHW + (size_t)(k * 64) * kHW + hw;
  const float* bp = bias0 + k * 64;                   // uniform -> s_load

  u64 m = 0;
#pragma unroll 32
  for (int i = 0; i < 64; ++i) {
    float v = __builtin_nontemporal_load(xp + (size_t)i * kHW) + bp[i];
    m |= (u64)(v >= 0.0f) << i;
  }
  u64* S = (u64*)(ws + OFF_S);
  S[(size_t)k * kP + p] = m;                          // 8B/lane, 512B/wave
}

// ---------------------------------------------------------------------------
// Kernel 2: global stats. thread = output channel o; positions addressed
// uniformly -> scalar s_load broadcasts of S (L2-hot); pure VALU xor/popc.
// ---------------------------------------------------------------------------
__global__ __launch_bounds__(256) void stats_kernel(char* __restrict__ ws) {
  int o = threadIdx.x;
  const u64* T = (const u64*)(ws + OFF_T);
  u64 t0 = T[o], t1 = T[256 + o], t2 = T[512 + o], t3 = T[768 + o];
  const u64* S = (const u64*)(ws + OFF_S);
  u32 pb = blockIdx.x * (u32)kPosSt;

  int summ = 0, summ2 = 0;
#pragma unroll 8
  for (int j = 0; j < kPosSt; j += 2) {
    u32 p = pb + j;                                  // uniform -> s_load_dwordx4
    U64x2 a0 = *(const U64x2*)&S[p];
    U64x2 a1 = *(const U64x2*)&S[kP + p];
    U64x2 a2 = *(const U64x2*)&S[2 * kP + p];
    U64x2 a3 = *(const U64x2*)&S[3 * kP + p];
    int ka = __popcll(a0.x ^ t0) + __popcll(a1.x ^ t1) +
             __popcll(a2.x ^ t2) + __popcll(a3.x ^ t3);
    int kb = __popcll(a0.y ^ t0) + __popcll(a1.y ^ t1) +
             __popcll(a2.y ^ t2) + __popcll(a3.y ^ t3);
    int ma = 128 - ka, mb = 128 - kb;
    summ  += ma + mb;
    summ2 += ma * ma + mb * mb;
  }
  atomicAdd((u64*)(ws + OFF_SUMD) + o,  (u64)(long long)(2 * summ));
  atomicAdd((u64*)(ws + OFF_SUMD2) + o, (u64)(long long)(4 * summ2));
}

// ---------------------------------------------------------------------------
// Kernel 3: BN coefs + fused epilogue. 1 position/lane, grid 1568.
//   u = 2*cA*m + cB + x ;  out = (u>0 ? u : alpha*u) + bias2
// x loads / out stores non-temporal (pure streams); S loads normal (L2-hot).
// ---------------------------------------------------------------------------
__global__ __launch_bounds__(256) void finalize_kernel(
    const float* __restrict__ x, const float* __restrict__ gamma,
    const float* __restrict__ beta, const float* __restrict__ bias1,
    const float* __restrict__ alpha, const float* __restrict__ bias2,
    const char* __restrict__ ws, float* __restrict__ out) {
  __shared__ u64    ldsT[256][4];   // [o][plane]: broadcast ds_read_b128 x2
  __shared__ float4 ldsC[256];      // {2*cA, cB, alpha, bias2}

  int t = threadIdx.x;
  {
    const u64* T = (const u64*)(ws + OFF_T);
#pragma unroll
    for (int q = 0; q < 4; ++q) ldsT[t][q] = T[q * 256 + t];

    const float*     scale = (const float*)(ws + OFF_SCALE);
    const long long* sumd  = (const long long*)(ws + OFF_SUMD);
    const long long* sumd2 = (const long long*)(ws + OFF_SUMD2);
    double inv  = 1.0 / (double)kP;
    double md   = (double)sumd[t] * inv;
    double e2   = (double)sumd2[t] * inv;
    double vard = e2 - md * md;
    float sc  = scale[t];
    float mu  = sc * (float)md;
    float var = sc * sc * (float)vard;
    float rs  = rsqrtf(var + 1e-5f);
    float g   = gamma[t];
    float cA  = g * rs * sc;
    float cB  = beta[t] - g * rs * mu + bias1[t];
    ldsC[t] = make_float4(2.0f * cA, cB, alpha[t], bias2[t]);
  }
  __syncthreads();

  int k    = __builtin_amdgcn_readfirstlane(t >> 6);
  int lane = t & 63;
  u32 p  = blockIdx.x * (u32)kPosPk + (u32)lane;
  u32 n  = p / kHW;
  u32 hw = p - n * kHW;

  const u64* S = (const u64*)(ws + OFF_S);
  u64 s0 = S[p];                       // 8B/lane coalesced, L2-hot
  u64 s1 = S[kP + p];
  u64 s2 = S[2 * kP + p];
  u64 s3 = S[3 * kP + p];

  const float* xp = x   + (size_t)n * kC * kHW + (size_t)(k * 64) * kHW + hw;
  float*       op = out + (size_t)n * kC * kHW + (size_t)(k * 64) * kHW + hw;

#pragma unroll 8
  for (int i = 0; i < 64; ++i) {
    int o = k * 64 + i;                // wave-uniform -> LDS broadcast
    u64 w0 = ldsT[o][0], w1 = ldsT[o][1], w2 = ldsT[o][2], w3 = ldsT[o][3];
    int kx = __popcll(s0 ^ w0) + __popcll(s1 ^ w1) +
             __popcll(s2 ^ w2) + __popcll(s3 ^ w3);
    float4 cc = ldsC[o];
    float xv = __builtin_nontemporal_load(xp + (size_t)i * kHW);
    float u  = fmaf(cc.x, (float)(128 - kx), cc.y) + xv;
    float r  = u > 0.0f ? u : cc.z * u;
    __builtin_nontemporal_store(r + cc.w, op + (size_t)i * kHW);
  }
}

extern "C" void kernel_launch(void* const* d_in, const int* in_sizes, int n_in,
                              void* d_out, int out_size, void* d_ws, size_t ws_size,
                              hipStream_t stream) {
  const float* x     = (const float*)d_in[0];
  const float* bias0 = (const float*)d_in[1];
  const float* w     = (const float*)d_in[2];
  const float* gamma = (const float*)d_in[3];
  const float* beta  = (const float*)d_in[4];
  const float* bias1 = (const float*)d_in[5];
  const float* alpha = (const float*)d_in[6];
  const float* bias2 = (const float*)d_in[7];
  float* out = (float*)d_out;
  char*  ws  = (char*)d_ws;

  hipLaunchKernelGGL(pack_kernel, dim3(kBlkPk), dim3(256), 0, stream,
                     x, bias0, w, ws);
  hipLaunchKernelGGL(stats_kernel, dim3(kBlkSt), dim3(256), 0, stream, ws);
  hipLaunchKernelGGL(finalize_kernel, dim3(kBlkPk), dim3(256), 0, stream,
                     x, gamma, beta, bias1, alpha, bias2, ws, out);
}